// Round 5
// baseline (439.783 us; speedup 1.0000x reference)
//
#include <hip/hip_runtime.h>
#include <cfloat>
#include <cmath>

// Adaptive log-softmax w/ loss, forward NLL. N=2048 rows.
// R5: 256x256 tiles (8 waves/block, 512 thr, each wave 128x64 output,
// 128KB LDS double-buffer), all three LSE GEMMs fused into ONE dispatch
// (blockIdx segment select + per-segment panel-pinned swizzle), both
// projections fused into one small dispatch. Counted vmcnt(8) pipeline.
// Split-precision 3-term bf16 MFMA: a*b ~= ah*bh + ah*bl + al*bh.

#define N_ROWS 2048
#define K_IN   1024
#define HEAD_O 4002
#define CUT0   4000
#define CUT1   20000
#define T0_O   16000
#define T1_O   30257
#define H0     512
#define H1     256

// 256-col tiles:
#define HT   16    // ceil(4002/256)
#define T0T  63    // ceil(16000/256)
#define T1T  119   // ceil(30257/256)

typedef __attribute__((ext_vector_type(8))) __bf16 bf16x8;
typedef __attribute__((ext_vector_type(4))) float f32x4;
typedef unsigned short u16;

// ---------------------------------------------------------------------------
__device__ inline u16 f2bf_rne(float f) {
    unsigned u = __builtin_bit_cast(unsigned, f);
    u += 0x7FFFu + ((u >> 16) & 1u);
    return (u16)(u >> 16);
}
__device__ inline float bf2f(u16 b) {
    return __builtin_bit_cast(float, (unsigned)b << 16);
}

__device__ inline void gload_lds16(const u16* g, u16* l) {
    __builtin_amdgcn_global_load_lds(
        (const __attribute__((address_space(1))) void*)g,
        (__attribute__((address_space(3))) void*)l, 16, 0, 0);
}

// ---------------------------------------------------------------------------
// Fused hi/lo split of all six fp32 operands.
// ---------------------------------------------------------------------------
__global__ __launch_bounds__(256)
void split_all(const float* __restrict__ s0, const float* __restrict__ s1,
               const float* __restrict__ s2, const float* __restrict__ s3,
               const float* __restrict__ s4, const float* __restrict__ s5,
               u16* __restrict__ h0, u16* __restrict__ l0,
               u16* __restrict__ h1, u16* __restrict__ l1,
               u16* __restrict__ h2, u16* __restrict__ l2,
               u16* __restrict__ h3, u16* __restrict__ l3,
               u16* __restrict__ h4, u16* __restrict__ l4,
               u16* __restrict__ h5, u16* __restrict__ l5)
{
    constexpr int e0 = (N_ROWS * K_IN) / 4;
    constexpr int e1 = e0 + (HEAD_O * K_IN) / 4;
    constexpr int e2 = e1 + (H0 * K_IN) / 4;
    constexpr int e3 = e2 + (H1 * K_IN) / 4;
    constexpr int e4 = e3 + (T0_O * H0) / 4;
    constexpr int e5 = e4 + (T1_O * H1) / 4;
    for (int i = blockIdx.x * 256 + threadIdx.x; i < e5; i += gridDim.x * 256) {
        const float* src; u16* h; u16* l; int off;
        if      (i < e0) { src = s0; h = h0; l = l0; off = i; }
        else if (i < e1) { src = s1; h = h1; l = l1; off = i - e0; }
        else if (i < e2) { src = s2; h = h2; l = l2; off = i - e1; }
        else if (i < e3) { src = s3; h = h3; l = l3; off = i - e2; }
        else if (i < e4) { src = s4; h = h4; l = l4; off = i - e3; }
        else             { src = s5; h = h5; l = l5; off = i - e4; }
        const float4 v = ((const float4*)src)[off];
        ushort4 hv, lv;
        hv.x = f2bf_rne(v.x); lv.x = f2bf_rne(v.x - bf2f(hv.x));
        hv.y = f2bf_rne(v.y); lv.y = f2bf_rne(v.y - bf2f(hv.y));
        hv.z = f2bf_rne(v.z); lv.z = f2bf_rne(v.z - bf2f(hv.z));
        hv.w = f2bf_rne(v.w); lv.w = f2bf_rne(v.w - bf2f(hv.w));
        ((ushort4*)h)[off] = hv; ((ushort4*)l)[off] = lv;
    }
}

// ---------------------------------------------------------------------------
// Row compaction (order irrelevant; per-row outputs are permutation-invariant).
// ---------------------------------------------------------------------------
__global__ __launch_bounds__(256)
void compact(const int* __restrict__ tgt, int* __restrict__ cnt,
             int* __restrict__ rowOf0, int* __restrict__ cidx0,
             int* __restrict__ rowOf1, int* __restrict__ cidx1)
{
    const int row = blockIdx.x * 256 + threadIdx.x;
    if (row >= N_ROWS) return;
    const int tg = tgt[row];
    if (tg >= CUT0 && tg < CUT1) {
        const int s = atomicAdd(&cnt[0], 1);
        rowOf0[s] = row; cidx0[row] = s;
    } else if (tg >= CUT1) {
        const int s = atomicAdd(&cnt[1], 1);
        rowOf1[s] = row; cidx1[row] = s;
    }
}

// ---------------------------------------------------------------------------
// Panel-pinned swizzle, 8 row-tiles per panel group: 64 consecutive bids =
// 8 panels x 8 rowts; same panel => same (bid & 7) => same XCD under
// round-robin. Tail (T % 8 panels) linear.
// ---------------------------------------------------------------------------
__device__ inline void map8(int bid, int T, int& panel, int& rowt)
{
    const int full = T & ~7;
    const int fb = full << 3;
    if (bid < fb) {
        panel = ((bid >> 6) << 3) + (bid & 7);
        rowt  = (bid >> 3) & 7;
    } else {
        const int l = bid - fb;
        panel = full + (l >> 3);
        rowt  = l & 7;
    }
}

// ---------------------------------------------------------------------------
// gemm256_core: D = X[M,K] @ W[O,K]^T on a 256x256 tile, 8 waves (2x4 grid,
// each wave 128x64 output = 8x4 fragments of 16x16), 3-term split-precision
// bf16 MFMA, 128KB LDS double-buffer, counted vmcnt(8).
// LDS buffer (64KB): Ah|Al|Bh|Bl planes of [256 rows][32 k] bf16, 16B k-slots
// XOR-swizzled (slot = kg ^ ((row>>1)&3)) via pre-swizzled GLOBAL sources.
//   LSE=true : per-row online-LSE partials (max,sumexp) -> Pm/Ps (stride T).
//   LSE=false: store C fp32 + bf16 hi/lo planes.
// ---------------------------------------------------------------------------
template<bool LSE>
__device__ __forceinline__ void gemm256_core(
    u16* lds,
    const u16* __restrict__ Ah, const u16* __restrict__ Al,
    const u16* __restrict__ Bh, const u16* __restrict__ Bl,
    int K, int O, int T, int bx, int by,
    const int* __restrict__ rowIdx,
    float* __restrict__ Pm, float* __restrict__ Ps,
    float* __restrict__ C, u16* __restrict__ Ch, u16* __restrict__ Cl)
{
    const int t = threadIdx.x;
    const int lane = t & 63;
    const int w = t >> 6;
    const int row0 = by * 256, col0 = bx * 256;
    const int kg = lane >> 4, li = lane & 15;
    const int wr = w >> 2, wc = w & 3;   // 2 x 4 wave grid

    // staging: 8 gload_lds per thread per K-step. Issue i: plane p=i>>1
    // (0=Ah,1=Al,2=Bh,3=Bl), half=i&1 (rows 0-127 / 128-255).
    const u16* gsrc[8];
    {
        const int slot = t & 3;
        const int rbase = t >> 2;                 // 0..127
        #pragma unroll
        for (int i = 0; i < 8; ++i) {
            const int p = i >> 1, half = i & 1;
            const int rl = half * 128 + rbase;
            const int kd = (slot ^ ((rl >> 1) & 3)) * 8;   // elems
            const u16* base; int grow;
            if (p < 2) {
                grow = row0 + rl;
                if (rowIdx) grow = rowIdx[grow] & (N_ROWS - 1);
                base = (p == 0) ? Ah : Al;
            } else {
                grow = col0 + rl; if (grow > O - 1) grow = O - 1;
                base = (p == 2) ? Bh : Bl;
            }
            gsrc[i] = base + (size_t)grow * K + kd;
        }
    }
    u16* ldsb = lds + t * 8;   // per-thread LDS base (wave-uniform + lane*16B)

    // fragment byte-offsets within a 64KB buffer
    int aoff[8], boff[4];
    #pragma unroll
    for (int m = 0; m < 8; ++m) {
        const int ar = wr * 128 + m * 16 + li;
        aoff[m] = ar * 64 + ((kg ^ ((ar >> 1) & 3)) << 4);            // Ah @ 0
    }
    #pragma unroll
    for (int n = 0; n < 4; ++n) {
        const int bc = wc * 64 + n * 16 + li;
        boff[n] = 32768 + bc * 64 + ((kg ^ ((bc >> 1) & 3)) << 4);    // Bh @ 32KB
    }

    f32x4 acc[8][4];
    #pragma unroll
    for (int m = 0; m < 8; ++m)
        #pragma unroll
        for (int n = 0; n < 4; ++n) acc[m][n] = (f32x4){0.f, 0.f, 0.f, 0.f};

    const char* ldsc = (const char*)lds;
    const int nsteps = K >> 5;   // >= 8 for all our K

    auto compute_step = [&](const char* bufc) {
        bf16x8 fbh[4], fbl[4];
        #pragma unroll
        for (int n = 0; n < 4; ++n) {
            fbh[n] = *(const bf16x8*)(bufc + boff[n]);
            fbl[n] = *(const bf16x8*)(bufc + boff[n] + 16384);
        }
        __builtin_amdgcn_s_setprio(1);
        #pragma unroll
        for (int m = 0; m < 8; ++m) {
            const bf16x8 fah = *(const bf16x8*)(bufc + aoff[m]);
            const bf16x8 fal = *(const bf16x8*)(bufc + aoff[m] + 16384);
            #pragma unroll
            for (int n = 0; n < 4; ++n) {
                acc[m][n] = __builtin_amdgcn_mfma_f32_16x16x32_bf16(fah, fbh[n], acc[m][n], 0, 0, 0);
                acc[m][n] = __builtin_amdgcn_mfma_f32_16x16x32_bf16(fah, fbl[n], acc[m][n], 0, 0, 0);
                acc[m][n] = __builtin_amdgcn_mfma_f32_16x16x32_bf16(fal, fbh[n], acc[m][n], 0, 0, 0);
            }
        }
        __builtin_amdgcn_s_setprio(0);
    };

    // prologue: stage buf0 (8 loads outstanding)
    #pragma unroll
    for (int i = 0; i < 8; ++i)
        gload_lds16(gsrc[i], ldsb + (i >> 1) * 8192 + (i & 1) * 4096);

    for (int ks = 0; ks < nsteps - 1; ++ks) {
        const int cur = ks & 1;
        {   // issue next tile into the other buffer (16 outstanding)
            const int nxt = (cur ^ 1) * 32768;   // shorts
            const int kof = (ks + 1) * 32;
            #pragma unroll
            for (int i = 0; i < 8; ++i)
                gload_lds16(gsrc[i] + kof, ldsb + nxt + (i >> 1) * 8192 + (i & 1) * 4096);
        }
        asm volatile("s_waitcnt vmcnt(8)" ::: "memory");  // cur's 8 landed
        __builtin_amdgcn_s_barrier();                     // ... in every wave
        compute_step(ldsc + cur * 65536);
        asm volatile("" ::: "memory");                    // pin reads above bar
        __builtin_amdgcn_s_barrier();                     // reads done before overwrite
    }
    // peeled last step
    asm volatile("s_waitcnt vmcnt(0)" ::: "memory");
    __builtin_amdgcn_s_barrier();
    compute_step(ldsc + ((nsteps - 1) & 1) * 65536);
    asm volatile("" ::: "memory");
    __builtin_amdgcn_s_barrier();                         // before LDS reuse

    if (LSE) {
        // C/D layout (HW-verified): col = li, row = kg*4 + reg.
        float* pmS = (float*)lds;            // [256][4]
        float* psS = (float*)lds + 1024;
        #pragma unroll
        for (int m = 0; m < 8; ++m) {
            #pragma unroll
            for (int r = 0; r < 4; ++r) {
                const int row_l = wr * 128 + m * 16 + kg * 4 + r;
                float mx = -FLT_MAX, sm = 0.f;
                float vv[4]; bool ok[4];
                #pragma unroll
                for (int n = 0; n < 4; ++n) {
                    const int c = col0 + wc * 64 + n * 16 + li;
                    ok[n] = (c < O);
                    vv[n] = acc[m][n][r];
                    if (ok[n]) mx = fmaxf(mx, vv[n]);
                }
                #pragma unroll
                for (int n = 0; n < 4; ++n)
                    if (ok[n]) sm += __expf(vv[n] - mx);
                #pragma unroll
                for (int off = 1; off < 16; off <<= 1) {   // 16 col-lanes
                    const float mo = __shfl_xor(mx, off);
                    const float so = __shfl_xor(sm, off);
                    const float M2 = fmaxf(mx, mo);
                    sm = sm * __expf(mx - M2) + so * __expf(mo - M2);
                    mx = M2;
                }
                if (li == 0) { pmS[row_l * 4 + wc] = mx; psS[row_l * 4 + wc] = sm; }
            }
        }
        __syncthreads();
        if (t < 256) {
            float M = -FLT_MAX, S = 0.f;
            #pragma unroll
            for (int q = 0; q < 4; ++q) {
                const float mq = pmS[t * 4 + q], sq = psS[t * 4 + q];
                const float M2 = fmaxf(M, mq);
                S = S * __expf(M - M2) + sq * __expf(mq - M2);
                M = M2;
            }
            Pm[(size_t)(row0 + t) * T + bx] = M;
            Ps[(size_t)(row0 + t) * T + bx] = S;
        }
    } else {
        // projection epilogue (O % 256 == 0): fp32 + bf16 hi/lo planes
        #pragma unroll
        for (int m = 0; m < 8; ++m)
            #pragma unroll
            for (int n = 0; n < 4; ++n)
                #pragma unroll
                for (int r = 0; r < 4; ++r) {
                    const int row = row0 + wr * 128 + m * 16 + kg * 4 + r;
                    const int col = col0 + wc * 64 + n * 16 + li;
                    const float v = acc[m][n][r];
                    const size_t idx = (size_t)row * O + col;
                    C[idx] = v;
                    const u16 h = f2bf_rne(v);
                    Ch[idx] = h;
                    Cl[idx] = f2bf_rne(v - bf2f(h));
                }
    }
}

// ---------------------------------------------------------------------------
// Fused LSE dispatch: head | tail0 | tail1 segments by blockIdx.
// ---------------------------------------------------------------------------
__global__ __launch_bounds__(512, 2)
void lse_fused(const u16* __restrict__ ih,   const u16* __restrict__ il,
               const u16* __restrict__ hwh,  const u16* __restrict__ hwl,
               const u16* __restrict__ t0hh, const u16* __restrict__ t0hl,
               const u16* __restrict__ w20h, const u16* __restrict__ w20l,
               const u16* __restrict__ t1hh, const u16* __restrict__ t1hl,
               const u16* __restrict__ w21h, const u16* __restrict__ w21l,
               const int* __restrict__ cnt,
               float* __restrict__ hPm, float* __restrict__ hPs,
               float* __restrict__ p0m, float* __restrict__ p0s,
               float* __restrict__ p1m, float* __restrict__ p1s)
{
    __shared__ u16 lds[65536];   // 128 KB
    const int bid = blockIdx.x;
    int bx, by;
    if (bid < HT * 8) {                                     // head: 128 blocks
        map8(bid, HT, bx, by);
        gemm256_core<true>(lds, ih, il, hwh, hwl, K_IN, HEAD_O, HT, bx, by,
                           nullptr, hPm, hPs, nullptr, nullptr, nullptr);
    } else if (bid < HT * 8 + T0T * 8) {                    // tail0: 504
        map8(bid - HT * 8, T0T, bx, by);
        if (by * 256 >= cnt[0]) return;
        gemm256_core<true>(lds, t0hh, t0hl, w20h, w20l, H0, T0_O, T0T, bx, by,
                           nullptr, p0m, p0s, nullptr, nullptr, nullptr);
    } else {                                                // tail1: 952
        map8(bid - HT * 8 - T0T * 8, T1T, bx, by);
        if (by * 256 >= cnt[1]) return;
        gemm256_core<true>(lds, t1hh, t1hl, w21h, w21l, H1, T1_O, T1T, bx, by,
                           nullptr, p1m, p1s, nullptr, nullptr, nullptr);
    }
}

// ---------------------------------------------------------------------------
// Fused projection dispatch: t0 (16 blocks) | t1 (8 blocks).
// ---------------------------------------------------------------------------
__global__ __launch_bounds__(512, 2)
void proj_fused(const u16* __restrict__ ih,   const u16* __restrict__ il,
                const u16* __restrict__ w10h, const u16* __restrict__ w10l,
                const u16* __restrict__ w11h, const u16* __restrict__ w11l,
                const int* __restrict__ cnt,
                const int* __restrict__ rowOf0, const int* __restrict__ rowOf1,
                float* __restrict__ t0h, u16* __restrict__ t0hh, u16* __restrict__ t0hl,
                float* __restrict__ t1h, u16* __restrict__ t1hh, u16* __restrict__ t1hl)
{
    __shared__ u16 lds[65536];
    const int bid = blockIdx.x;
    if (bid < 16) {                      // t0 proj: O=512 -> 2 col-tiles x 8 rowts
        const int bx = bid >> 3, by = bid & 7;
        if (by * 256 >= cnt[0]) return;
        gemm256_core<false>(lds, ih, il, w10h, w10l, K_IN, H0, 2, bx, by,
                            rowOf0, nullptr, nullptr, t0h, t0hh, t0hl);
    } else {                             // t1 proj: O=256 -> 1 col-tile x 8 rowts
        const int by = (bid - 16) & 7;
        if (by * 256 >= cnt[1]) return;
        gemm256_core<false>(lds, ih, il, w11h, w11l, K_IN, H1, 1, 0, by,
                            rowOf1, nullptr, nullptr, t1h, t1hh, t1hl);
    }
}

// ---------------------------------------------------------------------------
// finalize (R4-verified; tail data at compacted slots)
// ---------------------------------------------------------------------------
__device__ inline float block_sum(float v, float* sm)
{
#pragma unroll
    for (int off = 32; off > 0; off >>= 1) v += __shfl_xor(v, off);
    __syncthreads();
    if ((threadIdx.x & 63) == 0) sm[threadIdx.x >> 6] = v;
    __syncthreads();
    return sm[0] + sm[1] + sm[2] + sm[3];
}

__device__ inline void block_lse(float& m, float& s, float* smm, float* sms)
{
#pragma unroll
    for (int off = 32; off > 0; off >>= 1) {
        const float mo = __shfl_xor(m, off);
        const float so = __shfl_xor(s, off);
        const float M2 = fmaxf(m, mo);
        s = s * __expf(m - M2) + so * __expf(mo - M2);
        m = M2;
    }
    __syncthreads();
    if ((threadIdx.x & 63) == 0) { smm[threadIdx.x >> 6] = m; sms[threadIdx.x >> 6] = s; }
    __syncthreads();
    const float M2 = fmaxf(fmaxf(smm[0], smm[1]), fmaxf(smm[2], smm[3]));
    const float S  = sms[0] * __expf(smm[0] - M2) + sms[1] * __expf(smm[1] - M2)
                   + sms[2] * __expf(smm[2] - M2) + sms[3] * __expf(smm[3] - M2);
    m = M2; s = S;
}

__device__ inline void local_lse(const float* __restrict__ Pm,
                                 const float* __restrict__ Ps,
                                 int T, float& m, float& s)
{
    m = -FLT_MAX; s = 0.f;
    for (int i = threadIdx.x; i < T; i += 256) {
        const float mi = Pm[i], si = Ps[i];
        const float M2 = fmaxf(m, mi);
        s = s * __expf(m - M2) + si * __expf(mi - M2);
        m = M2;
    }
}

__global__ __launch_bounds__(256)
void finalize(const float* __restrict__ inp, const int* __restrict__ tgt,
              const float* __restrict__ head_w,
              const int* __restrict__ cidx0, const int* __restrict__ cidx1,
              const float* __restrict__ t0h, const float* __restrict__ t1h,
              const float* __restrict__ hPm, const float* __restrict__ hPs, int hT,
              const float* __restrict__ p0m, const float* __restrict__ p0s, int T0,
              const float* __restrict__ p1m, const float* __restrict__ p1s, int T1,
              const float* __restrict__ t0_w2, const float* __restrict__ t1_w2,
              float* __restrict__ out)
{
    __shared__ float sm[4], ss[4];
    const int row = blockIdx.x, t = threadIdx.x;
    const int tg = tgt[row];
    const bool in1 = (tg >= CUT0) && (tg < CUT1);
    const bool in2 = (tg >= CUT1);
    const int g = (tg < CUT0) ? tg : (in1 ? CUT0 : CUT0 + 1);
    const int c0 = in1 ? cidx0[row] : 0;
    const int c1 = in2 ? cidx1[row] : 0;

    float d;
    {
        const float4 a = *(const float4*)(inp + (size_t)row * K_IN + t * 4);
        const float4 b = *(const float4*)(head_w + (size_t)g * K_IN + t * 4);
        d = a.x * b.x + a.y * b.y + a.z * b.z + a.w * b.w;
    }
    const float dot_h = block_sum(d, sm);

    int r0 = tg - CUT0; r0 = r0 < 0 ? 0 : (r0 > T0_O - 1 ? T0_O - 1 : r0);
    d = 0.f;
    if (t < 128) {
        const float4 a = *(const float4*)(t0h + (size_t)c0 * H0 + t * 4);
        const float4 b = *(const float4*)(t0_w2 + (size_t)r0 * H0 + t * 4);
        d = a.x * b.x + a.y * b.y + a.z * b.z + a.w * b.w;
    }
    const float dot0 = block_sum(d, sm);

    int r1 = tg - CUT1; r1 = r1 < 0 ? 0 : (r1 > T1_O - 1 ? T1_O - 1 : r1);
    d = 0.f;
    if (t < 64) {
        const float4 a = *(const float4*)(t1h + (size_t)c1 * H1 + t * 4);
        const float4 b = *(const float4*)(t1_w2 + (size_t)r1 * H1 + t * 4);
        d = a.x * b.x + a.y * b.y + a.z * b.z + a.w * b.w;
    }
    const float dot1 = block_sum(d, sm);

    float m, s;
    local_lse(hPm + (size_t)row * hT, hPs + (size_t)row * hT, hT, m, s);
    block_lse(m, s, sm, ss);
    const float lse_h = m + logf(s);

    local_lse(p0m + (size_t)c0 * T0, p0s + (size_t)c0 * T0, T0, m, s);
    block_lse(m, s, sm, ss);
    const float lse_0 = m + logf(s);

    local_lse(p1m + (size_t)c1 * T1, p1s + (size_t)c1 * T1, T1, m, s);
    block_lse(m, s, sm, ss);
    const float lse_1 = m + logf(s);

    if (t == 0) {
        float res = dot_h - lse_h;
        if (in1) res += dot0 - lse_0;
        if (in2) res += dot1 - lse_1;
        out[row] = -res;
    }
}

// ---------------------------------------------------------------------------
extern "C" void kernel_launch(void* const* d_in, const int* in_sizes, int n_in,
                              void* d_out, int out_size, void* d_ws, size_t ws_size,
                              hipStream_t stream)
{
    const float* inp    = (const float*)d_in[0];
    const int*   tgt    = (const int*)  d_in[1];
    const float* head_w = (const float*)d_in[2];
    const float* t0_w1  = (const float*)d_in[3];
    const float* t0_w2  = (const float*)d_in[4];
    const float* t1_w1  = (const float*)d_in[5];
    const float* t1_w2  = (const float*)d_in[6];
    float* out = (float*)d_out;

    char* p = (char*)d_ws;
    #define ALLOC(name, type, count) \
        type* name = (type*)p; p += (((size_t)(count) * sizeof(type)) + 255) & ~(size_t)255;
    ALLOC(t0h,  float, (size_t)N_ROWS * H0)
    ALLOC(t1h,  float, (size_t)N_ROWS * H1)
    ALLOC(hPm,  float, (size_t)N_ROWS * HT)
    ALLOC(hPs,  float, (size_t)N_ROWS * HT)
    ALLOC(p0m,  float, (size_t)N_ROWS * T0T)
    ALLOC(p0s,  float, (size_t)N_ROWS * T0T)
    ALLOC(p1m,  float, (size_t)N_ROWS * T1T)
    ALLOC(p1s,  float, (size_t)N_ROWS * T1T)
    ALLOC(ih,   u16, (size_t)N_ROWS * K_IN)
    ALLOC(il,   u16, (size_t)N_ROWS * K_IN)
    ALLOC(hwh,  u16, (size_t)HEAD_O * K_IN)
    ALLOC(hwl,  u16, (size_t)HEAD_O * K_IN)
    ALLOC(w10h, u16, (size_t)H0 * K_IN)
    ALLOC(w10l, u16, (size_t)H0 * K_IN)
    ALLOC(w11h, u16, (size_t)H1 * K_IN)
    ALLOC(w11l, u16, (size_t)H1 * K_IN)
    ALLOC(w20h, u16, (size_t)T0_O * H0)
    ALLOC(w20l, u16, (size_t)T0_O * H0)
    ALLOC(w21h, u16, (size_t)T1_O * H1)
    ALLOC(w21l, u16, (size_t)T1_O * H1)
    ALLOC(t0hh, u16, (size_t)N_ROWS * H0)
    ALLOC(t0hl, u16, (size_t)N_ROWS * H0)
    ALLOC(t1hh, u16, (size_t)N_ROWS * H1)
    ALLOC(t1hl, u16, (size_t)N_ROWS * H1)
    ALLOC(cnt,    int, 2)
    ALLOC(rowOf0, int, N_ROWS)
    ALLOC(cidx0,  int, N_ROWS)
    ALLOC(rowOf1, int, N_ROWS)
    ALLOC(cidx1,  int, N_ROWS)
    #undef ALLOC

    hipMemsetAsync(cnt, 0, 2 * sizeof(int), stream);
    compact<<<dim3(N_ROWS / 256), dim3(256), 0, stream>>>(tgt, cnt, rowOf0, cidx0, rowOf1, cidx1);

    split_all<<<dim3(2048), dim3(256), 0, stream>>>(
        inp, head_w, t0_w1, t1_w1, t0_w2, t1_w2,
        ih, il, hwh, hwl, w10h, w10l, w11h, w11l, w20h, w20l, w21h, w21l);

    // projections (compacted, gathered A) -> fp32 + hi/lo planes
    proj_fused<<<dim3(24), dim3(512), 0, stream>>>(
        ih, il, w10h, w10l, w11h, w11l, cnt, rowOf0, rowOf1,
        t0h, t0hh, t0hl, t1h, t1hh, t1hl);

    // fused head + tail0 + tail1 LSE GEMMs
    lse_fused<<<dim3(HT * 8 + T0T * 8 + T1T * 8), dim3(512), 0, stream>>>(
        ih, il, hwh, hwl, t0hh, t0hl, w20h, w20l, t1hh, t1hl, w21h, w21l,
        cnt, hPm, hPs, p0m, p0s, p1m, p1s);

    // per-row assembly
    finalize<<<dim3(N_ROWS), dim3(256), 0, stream>>>(
        inp, tgt, head_w, cidx0, cidx1, t0h, t1h,
        hPm, hPs, HT, p0m, p0s, T0T, p1m, p1s, T1T, t0_w2, t1_w2, out);
}

// Round 6
// 305.265 us; speedup vs baseline: 1.4407x; 1.4407x over previous
//
#include <hip/hip_runtime.h>
#include <cfloat>
#include <cmath>

// Adaptive log-softmax w/ loss, forward NLL. N=2048 rows.
// R6: pure-bf16 MFMA (1-term; error ~1e-3 << comparison granularity observed
// across R1-R5), 64KB LDS double-buffer -> 2 blocks/CU, head GEMM + both
// projections packed into one dispatch, tails in a second. Counted vmcnt(4),
// pre-swizzled conflict-free staging, panel-pinned swizzle, row compaction.

#define N_ROWS 2048
#define K_IN   1024
#define HEAD_O 4002
#define CUT0   4000
#define CUT1   20000
#define T0_O   16000
#define T1_O   30257
#define H0     512
#define H1     256

// 256-col tiles:
#define HT   16    // ceil(4002/256)
#define T0T  63    // ceil(16000/256)
#define T1T  119   // ceil(30257/256)

typedef __attribute__((ext_vector_type(8))) __bf16 bf16x8;
typedef __attribute__((ext_vector_type(4))) float f32x4;
typedef unsigned short u16;

// ---------------------------------------------------------------------------
__device__ inline u16 f2bf_rne(float f) {
    unsigned u = __builtin_bit_cast(unsigned, f);
    u += 0x7FFFu + ((u >> 16) & 1u);
    return (u16)(u >> 16);
}
__device__ inline float bf2f(u16 b) {
    return __builtin_bit_cast(float, (unsigned)b << 16);
}

__device__ inline void gload_lds16(const u16* g, u16* l) {
    __builtin_amdgcn_global_load_lds(
        (const __attribute__((address_space(1))) void*)g,
        (__attribute__((address_space(3))) void*)l, 16, 0, 0);
}

// ---------------------------------------------------------------------------
// Fused bf16 conversion of all six fp32 operands (hi plane only).
// ---------------------------------------------------------------------------
__global__ __launch_bounds__(256)
void split_all(const float* __restrict__ s0, const float* __restrict__ s1,
               const float* __restrict__ s2, const float* __restrict__ s3,
               const float* __restrict__ s4, const float* __restrict__ s5,
               u16* __restrict__ h0, u16* __restrict__ h1, u16* __restrict__ h2,
               u16* __restrict__ h3, u16* __restrict__ h4, u16* __restrict__ h5)
{
    constexpr int e0 = (N_ROWS * K_IN) / 4;
    constexpr int e1 = e0 + (HEAD_O * K_IN) / 4;
    constexpr int e2 = e1 + (H0 * K_IN) / 4;
    constexpr int e3 = e2 + (H1 * K_IN) / 4;
    constexpr int e4 = e3 + (T0_O * H0) / 4;
    constexpr int e5 = e4 + (T1_O * H1) / 4;
    for (int i = blockIdx.x * 256 + threadIdx.x; i < e5; i += gridDim.x * 256) {
        const float* src; u16* h; int off;
        if      (i < e0) { src = s0; h = h0; off = i; }
        else if (i < e1) { src = s1; h = h1; off = i - e0; }
        else if (i < e2) { src = s2; h = h2; off = i - e1; }
        else if (i < e3) { src = s3; h = h3; off = i - e2; }
        else if (i < e4) { src = s4; h = h4; off = i - e3; }
        else             { src = s5; h = h5; off = i - e4; }
        const float4 v = ((const float4*)src)[off];
        ushort4 hv;
        hv.x = f2bf_rne(v.x); hv.y = f2bf_rne(v.y);
        hv.z = f2bf_rne(v.z); hv.w = f2bf_rne(v.w);
        ((ushort4*)h)[off] = hv;
    }
}

// ---------------------------------------------------------------------------
// Row compaction (order irrelevant; per-row outputs permutation-invariant).
// ---------------------------------------------------------------------------
__global__ __launch_bounds__(256)
void compact(const int* __restrict__ tgt, int* __restrict__ cnt,
             int* __restrict__ rowOf0, int* __restrict__ cidx0,
             int* __restrict__ rowOf1, int* __restrict__ cidx1)
{
    const int row = blockIdx.x * 256 + threadIdx.x;
    if (row >= N_ROWS) return;
    const int tg = tgt[row];
    if (tg >= CUT0 && tg < CUT1) {
        const int s = atomicAdd(&cnt[0], 1);
        rowOf0[s] = row; cidx0[row] = s;
    } else if (tg >= CUT1) {
        const int s = atomicAdd(&cnt[1], 1);
        rowOf1[s] = row; cidx1[row] = s;
    }
}

// ---------------------------------------------------------------------------
// Panel-pinned swizzle: 64 consecutive bids = 8 panels x 8 rowts (same panel
// => same XCD under round-robin). Tail (T % 8) linear.
// ---------------------------------------------------------------------------
__device__ inline void map8(int bid, int T, int& panel, int& rowt)
{
    const int full = T & ~7;
    const int fb = full << 3;
    if (bid < fb) {
        panel = ((bid >> 6) << 3) + (bid & 7);
        rowt  = (bid >> 3) & 7;
    } else {
        const int l = bid - fb;
        panel = full + (l >> 3);
        rowt  = l & 7;
    }
}

// ---------------------------------------------------------------------------
// gemm256_core: D = A[M,K] @ B[O,K]^T (bf16 in, fp32 acc) on a 256x256 tile,
// 8 waves (2x4), each wave 128x64 output (8x4 fragments of 16x16x32).
// 64KB LDS double-buffer (2 x {A plane 16KB | B plane 16KB}), counted
// vmcnt(4). 16B k-slots XOR-swizzled (slot = kg ^ ((row>>1)&3)) via
// pre-swizzled GLOBAL sources (global_load_lds writes linearly).
//   LSE=true : per-row online-LSE partials (max,sumexp) -> Pm/Ps (stride T).
//   LSE=false: store bf16 C (hi plane) -> Ch.
// ---------------------------------------------------------------------------
template<bool LSE>
__device__ __forceinline__ void gemm256_core(
    u16* lds,
    const u16* __restrict__ A, const u16* __restrict__ B,
    int K, int O, int T, int bx, int by,
    const int* __restrict__ rowIdx,
    float* __restrict__ Pm, float* __restrict__ Ps,
    u16* __restrict__ Ch)
{
    const int t = threadIdx.x;
    const int lane = t & 63;
    const int w = t >> 6;
    const int row0 = by * 256, col0 = bx * 256;
    const int kg = lane >> 4, li = lane & 15;
    const int wr = w >> 2, wc = w & 3;   // 2 x 4 wave grid

    // staging: 4 gload_lds per thread per K-step (2 planes x 2 row-halves)
    const u16* gsrc[4];
    {
        const int slot = t & 3;
        const int rbase = t >> 2;                 // 0..127
        #pragma unroll
        for (int i = 0; i < 4; ++i) {
            const int p = i >> 1, half = i & 1;
            const int rl = half * 128 + rbase;
            const int kd = (slot ^ ((rl >> 1) & 3)) * 8;   // elems
            const u16* base; int grow;
            if (p == 0) {
                grow = row0 + rl;
                if (rowIdx) grow = rowIdx[grow] & (N_ROWS - 1);
                base = A;
            } else {
                grow = col0 + rl; if (grow > O - 1) grow = O - 1;
                base = B;
            }
            gsrc[i] = base + (size_t)grow * K + kd;
        }
    }
    u16* ldsb = lds + t * 8;   // linear per-thread LDS dest

    // fragment byte-offsets within a 32KB buffer (A @ 0, B @ 16KB)
    int aoff[8], boff[4];
    #pragma unroll
    for (int m = 0; m < 8; ++m) {
        const int ar = wr * 128 + m * 16 + li;
        aoff[m] = ar * 64 + ((kg ^ ((ar >> 1) & 3)) << 4);
    }
    #pragma unroll
    for (int n = 0; n < 4; ++n) {
        const int bc = wc * 64 + n * 16 + li;
        boff[n] = 16384 + bc * 64 + ((kg ^ ((bc >> 1) & 3)) << 4);
    }

    f32x4 acc[8][4];
    #pragma unroll
    for (int m = 0; m < 8; ++m)
        #pragma unroll
        for (int n = 0; n < 4; ++n) acc[m][n] = (f32x4){0.f, 0.f, 0.f, 0.f};

    const char* ldsc = (const char*)lds;
    const int nsteps = K >> 5;   // 32 / 16 / 8

    auto compute_step = [&](const char* bufc) {
        bf16x8 fb[4];
        #pragma unroll
        for (int n = 0; n < 4; ++n) fb[n] = *(const bf16x8*)(bufc + boff[n]);
        __builtin_amdgcn_s_setprio(1);
        #pragma unroll
        for (int m = 0; m < 8; ++m) {
            const bf16x8 fa = *(const bf16x8*)(bufc + aoff[m]);
            #pragma unroll
            for (int n = 0; n < 4; ++n)
                acc[m][n] = __builtin_amdgcn_mfma_f32_16x16x32_bf16(fa, fb[n], acc[m][n], 0, 0, 0);
        }
        __builtin_amdgcn_s_setprio(0);
    };

    // prologue: stage buf0 (4 loads outstanding)
    #pragma unroll
    for (int i = 0; i < 4; ++i)
        gload_lds16(gsrc[i], ldsb + (i >> 1) * 8192 + (i & 1) * 4096);

    for (int ks = 0; ks < nsteps - 1; ++ks) {
        const int cur = ks & 1;
        {   // issue next tile into the other buffer (8 outstanding)
            const int nxt = (cur ^ 1) * 16384;   // shorts
            const int kof = (ks + 1) * 32;
            #pragma unroll
            for (int i = 0; i < 4; ++i)
                gload_lds16(gsrc[i] + kof, ldsb + nxt + (i >> 1) * 8192 + (i & 1) * 4096);
        }
        asm volatile("s_waitcnt vmcnt(4)" ::: "memory");  // cur's 4 landed
        __builtin_amdgcn_s_barrier();                     // ... in every wave
        compute_step(ldsc + cur * 32768);
        asm volatile("" ::: "memory");                    // pin reads above bar
        __builtin_amdgcn_s_barrier();                     // reads done before overwrite
    }
    // peeled last step
    asm volatile("s_waitcnt vmcnt(0)" ::: "memory");
    __builtin_amdgcn_s_barrier();
    compute_step(ldsc + ((nsteps - 1) & 1) * 32768);
    asm volatile("" ::: "memory");
    __builtin_amdgcn_s_barrier();                         // before LDS reuse

    if (LSE) {
        // C/D layout (HW-verified): col = li, row = kg*4 + reg.
        float* pmS = (float*)lds;            // [256][4]
        float* psS = (float*)lds + 1024;
        #pragma unroll
        for (int m = 0; m < 8; ++m) {
            #pragma unroll
            for (int r = 0; r < 4; ++r) {
                const int row_l = wr * 128 + m * 16 + kg * 4 + r;
                float mx = -FLT_MAX, sm = 0.f;
                float vv[4]; bool ok[4];
                #pragma unroll
                for (int n = 0; n < 4; ++n) {
                    const int c = col0 + wc * 64 + n * 16 + li;
                    ok[n] = (c < O);
                    vv[n] = acc[m][n][r];
                    if (ok[n]) mx = fmaxf(mx, vv[n]);
                }
                #pragma unroll
                for (int n = 0; n < 4; ++n)
                    if (ok[n]) sm += __expf(vv[n] - mx);
                #pragma unroll
                for (int off = 1; off < 16; off <<= 1) {   // 16 col-lanes
                    const float mo = __shfl_xor(mx, off);
                    const float so = __shfl_xor(sm, off);
                    const float M2 = fmaxf(mx, mo);
                    sm = sm * __expf(mx - M2) + so * __expf(mo - M2);
                    mx = M2;
                }
                if (li == 0) { pmS[row_l * 4 + wc] = mx; psS[row_l * 4 + wc] = sm; }
            }
        }
        __syncthreads();
        if (t < 256) {
            float M = -FLT_MAX, S = 0.f;
            #pragma unroll
            for (int q = 0; q < 4; ++q) {
                const float mq = pmS[t * 4 + q], sq = psS[t * 4 + q];
                const float M2 = fmaxf(M, mq);
                S = S * __expf(M - M2) + sq * __expf(mq - M2);
                M = M2;
            }
            Pm[(size_t)(row0 + t) * T + bx] = M;
            Ps[(size_t)(row0 + t) * T + bx] = S;
        }
    } else {
        // projection epilogue (O % 256 == 0): bf16 hi plane only
        #pragma unroll
        for (int m = 0; m < 8; ++m)
            #pragma unroll
            for (int n = 0; n < 4; ++n)
                #pragma unroll
                for (int r = 0; r < 4; ++r) {
                    const int row = row0 + wr * 128 + m * 16 + kg * 4 + r;
                    const int col = col0 + wc * 64 + n * 16 + li;
                    Ch[(size_t)row * O + col] = f2bf_rne(acc[m][n][r]);
                }
    }
}

// ---------------------------------------------------------------------------
// Dispatch 1: head LSE GEMM (128 blocks) + t0 projection (16) + t1 projection
// (8) — all depend only on splits; packed to fill the GPU.
// ---------------------------------------------------------------------------
__global__ __launch_bounds__(512)
void projhead(const u16* __restrict__ ih,   const u16* __restrict__ hwh,
              const u16* __restrict__ w10h, const u16* __restrict__ w11h,
              const int* __restrict__ cnt,
              const int* __restrict__ rowOf0, const int* __restrict__ rowOf1,
              float* __restrict__ hPm, float* __restrict__ hPs,
              u16* __restrict__ t0hh, u16* __restrict__ t1hh)
{
    __shared__ u16 lds[32768];   // 64 KB
    const int bid = blockIdx.x;
    int bx, by;
    if (bid < HT * 8) {
        map8(bid, HT, bx, by);
        gemm256_core<true>(lds, ih, hwh, K_IN, HEAD_O, HT, bx, by,
                           nullptr, hPm, hPs, nullptr);
    } else if (bid < HT * 8 + 16) {
        const int b = bid - HT * 8;
        bx = b >> 3; by = b & 7;
        if (by * 256 >= cnt[0]) return;
        gemm256_core<false>(lds, ih, w10h, K_IN, H0, 2, bx, by,
                            rowOf0, nullptr, nullptr, t0hh);
    } else {
        const int b = bid - HT * 8 - 16;
        by = b & 7;
        if (by * 256 >= cnt[1]) return;
        gemm256_core<false>(lds, ih, w11h, K_IN, H1, 1, 0, by,
                            rowOf1, nullptr, nullptr, t1hh);
    }
}

// ---------------------------------------------------------------------------
// Dispatch 2: tail LSE GEMMs on compacted rows.
// ---------------------------------------------------------------------------
__global__ __launch_bounds__(512)
void lse_tails(const u16* __restrict__ t0hh, const u16* __restrict__ w20h,
               const u16* __restrict__ t1hh, const u16* __restrict__ w21h,
               const int* __restrict__ cnt,
               float* __restrict__ p0m, float* __restrict__ p0s,
               float* __restrict__ p1m, float* __restrict__ p1s)
{
    __shared__ u16 lds[32768];
    const int bid = blockIdx.x;
    int bx, by;
    if (bid < T0T * 8) {
        map8(bid, T0T, bx, by);
        if (by * 256 >= cnt[0]) return;
        gemm256_core<true>(lds, t0hh, w20h, H0, T0_O, T0T, bx, by,
                           nullptr, p0m, p0s, nullptr);
    } else {
        map8(bid - T0T * 8, T1T, bx, by);
        if (by * 256 >= cnt[1]) return;
        gemm256_core<true>(lds, t1hh, w21h, H1, T1_O, T1T, bx, by,
                           nullptr, p1m, p1s, nullptr);
    }
}

// ---------------------------------------------------------------------------
// finalize: combine LSE partials + recompute gathered target logits.
// Tail hidden read from bf16 hi planes at compacted slots.
// ---------------------------------------------------------------------------
__device__ inline float block_sum(float v, float* sm)
{
#pragma unroll
    for (int off = 32; off > 0; off >>= 1) v += __shfl_xor(v, off);
    __syncthreads();
    if ((threadIdx.x & 63) == 0) sm[threadIdx.x >> 6] = v;
    __syncthreads();
    return sm[0] + sm[1] + sm[2] + sm[3];
}

__device__ inline void block_lse(float& m, float& s, float* smm, float* sms)
{
#pragma unroll
    for (int off = 32; off > 0; off >>= 1) {
        const float mo = __shfl_xor(m, off);
        const float so = __shfl_xor(s, off);
        const float M2 = fmaxf(m, mo);
        s = s * __expf(m - M2) + so * __expf(mo - M2);
        m = M2;
    }
    __syncthreads();
    if ((threadIdx.x & 63) == 0) { smm[threadIdx.x >> 6] = m; sms[threadIdx.x >> 6] = s; }
    __syncthreads();
    const float M2 = fmaxf(fmaxf(smm[0], smm[1]), fmaxf(smm[2], smm[3]));
    const float S  = sms[0] * __expf(smm[0] - M2) + sms[1] * __expf(smm[1] - M2)
                   + sms[2] * __expf(smm[2] - M2) + sms[3] * __expf(smm[3] - M2);
    m = M2; s = S;
}

__device__ inline void local_lse(const float* __restrict__ Pm,
                                 const float* __restrict__ Ps,
                                 int T, float& m, float& s)
{
    m = -FLT_MAX; s = 0.f;
    for (int i = threadIdx.x; i < T; i += 256) {
        const float mi = Pm[i], si = Ps[i];
        const float M2 = fmaxf(m, mi);
        s = s * __expf(m - M2) + si * __expf(mi - M2);
        m = M2;
    }
}

__global__ __launch_bounds__(256)
void finalize(const float* __restrict__ inp, const int* __restrict__ tgt,
              const float* __restrict__ head_w,
              const int* __restrict__ cidx0, const int* __restrict__ cidx1,
              const u16* __restrict__ t0hh, const u16* __restrict__ t1hh,
              const float* __restrict__ hPm, const float* __restrict__ hPs, int hT,
              const float* __restrict__ p0m, const float* __restrict__ p0s, int T0,
              const float* __restrict__ p1m, const float* __restrict__ p1s, int T1,
              const float* __restrict__ t0_w2, const float* __restrict__ t1_w2,
              float* __restrict__ out)
{
    __shared__ float sm[4], ss[4];
    const int row = blockIdx.x, t = threadIdx.x;
    const int tg = tgt[row];
    const bool in1 = (tg >= CUT0) && (tg < CUT1);
    const bool in2 = (tg >= CUT1);
    const int g = (tg < CUT0) ? tg : (in1 ? CUT0 : CUT0 + 1);
    const int c0 = in1 ? cidx0[row] : 0;
    const int c1 = in2 ? cidx1[row] : 0;

    float d;
    {
        const float4 a = *(const float4*)(inp + (size_t)row * K_IN + t * 4);
        const float4 b = *(const float4*)(head_w + (size_t)g * K_IN + t * 4);
        d = a.x * b.x + a.y * b.y + a.z * b.z + a.w * b.w;
    }
    const float dot_h = block_sum(d, sm);

    int r0 = tg - CUT0; r0 = r0 < 0 ? 0 : (r0 > T0_O - 1 ? T0_O - 1 : r0);
    d = 0.f;
    if (t < 128) {
        const ushort4 a = *(const ushort4*)(t0hh + (size_t)c0 * H0 + t * 4);
        const float4  b = *(const float4*)(t0_w2 + (size_t)r0 * H0 + t * 4);
        d = bf2f(a.x) * b.x + bf2f(a.y) * b.y + bf2f(a.z) * b.z + bf2f(a.w) * b.w;
    }
    const float dot0 = block_sum(d, sm);

    int r1 = tg - CUT1; r1 = r1 < 0 ? 0 : (r1 > T1_O - 1 ? T1_O - 1 : r1);
    d = 0.f;
    if (t < 64) {
        const ushort4 a = *(const ushort4*)(t1hh + (size_t)c1 * H1 + t * 4);
        const float4  b = *(const float4*)(t1_w2 + (size_t)r1 * H1 + t * 4);
        d = bf2f(a.x) * b.x + bf2f(a.y) * b.y + bf2f(a.z) * b.z + bf2f(a.w) * b.w;
    }
    const float dot1 = block_sum(d, sm);

    float m, s;
    local_lse(hPm + (size_t)row * hT, hPs + (size_t)row * hT, hT, m, s);
    block_lse(m, s, sm, ss);
    const float lse_h = m + logf(s);

    local_lse(p0m + (size_t)c0 * T0, p0s + (size_t)c0 * T0, T0, m, s);
    block_lse(m, s, sm, ss);
    const float lse_0 = m + logf(s);

    local_lse(p1m + (size_t)c1 * T1, p1s + (size_t)c1 * T1, T1, m, s);
    block_lse(m, s, sm, ss);
    const float lse_1 = m + logf(s);

    if (t == 0) {
        float res = dot_h - lse_h;
        if (in1) res += dot0 - lse_0;
        if (in2) res += dot1 - lse_1;
        out[row] = -res;
    }
}

// ---------------------------------------------------------------------------
extern "C" void kernel_launch(void* const* d_in, const int* in_sizes, int n_in,
                              void* d_out, int out_size, void* d_ws, size_t ws_size,
                              hipStream_t stream)
{
    const float* inp    = (const float*)d_in[0];
    const int*   tgt    = (const int*)  d_in[1];
    const float* head_w = (const float*)d_in[2];
    const float* t0_w1  = (const float*)d_in[3];
    const float* t0_w2  = (const float*)d_in[4];
    const float* t1_w1  = (const float*)d_in[5];
    const float* t1_w2  = (const float*)d_in[6];
    float* out = (float*)d_out;

    char* p = (char*)d_ws;
    #define ALLOC(name, type, count) \
        type* name = (type*)p; p += (((size_t)(count) * sizeof(type)) + 255) & ~(size_t)255;
    ALLOC(hPm,  float, (size_t)N_ROWS * HT)
    ALLOC(hPs,  float, (size_t)N_ROWS * HT)
    ALLOC(p0m,  float, (size_t)N_ROWS * T0T)
    ALLOC(p0s,  float, (size_t)N_ROWS * T0T)
    ALLOC(p1m,  float, (size_t)N_ROWS * T1T)
    ALLOC(p1s,  float, (size_t)N_ROWS * T1T)
    ALLOC(ih,   u16, (size_t)N_ROWS * K_IN)
    ALLOC(hwh,  u16, (size_t)HEAD_O * K_IN)
    ALLOC(w10h, u16, (size_t)H0 * K_IN)
    ALLOC(w11h, u16, (size_t)H1 * K_IN)
    ALLOC(w20h, u16, (size_t)T0_O * H0)
    ALLOC(w21h, u16, (size_t)T1_O * H1)
    ALLOC(t0hh, u16, (size_t)N_ROWS * H0)
    ALLOC(t1hh, u16, (size_t)N_ROWS * H1)
    ALLOC(cnt,    int, 2)
    ALLOC(rowOf0, int, N_ROWS)
    ALLOC(cidx0,  int, N_ROWS)
    ALLOC(rowOf1, int, N_ROWS)
    ALLOC(cidx1,  int, N_ROWS)
    #undef ALLOC

    hipMemsetAsync(cnt, 0, 2 * sizeof(int), stream);
    compact<<<dim3(N_ROWS / 256), dim3(256), 0, stream>>>(tgt, cnt, rowOf0, cidx0, rowOf1, cidx1);

    split_all<<<dim3(2048), dim3(256), 0, stream>>>(
        inp, head_w, t0_w1, t1_w1, t0_w2, t1_w2,
        ih, hwh, w10h, w11h, w20h, w21h);

    // head LSE + both projections (all depend only on splits)
    projhead<<<dim3(HT * 8 + 16 + 8), dim3(512), 0, stream>>>(
        ih, hwh, w10h, w11h, cnt, rowOf0, rowOf1, hPm, hPs, t0hh, t1hh);

    // tail LSE GEMMs
    lse_tails<<<dim3(T0T * 8 + T1T * 8), dim3(512), 0, stream>>>(
        t0hh, w20h, t1hh, w21h, cnt, p0m, p0s, p1m, p1s);

    // per-row assembly
    finalize<<<dim3(N_ROWS), dim3(256), 0, stream>>>(
        inp, tgt, head_w, cidx0, cidx1, t0hh, t1hh,
        hPm, hPs, HT, p0m, p0s, T0T, p1m, p1s, T1T, t0_w2, t1_w2, out);
}

// Round 8
// 302.173 us; speedup vs baseline: 1.4554x; 1.0102x over previous
//
#include <hip/hip_runtime.h>
#include <cfloat>
#include <cmath>

// Adaptive log-softmax w/ loss, forward NLL. N=2048 rows.
// R7 (resubmit; prior attempt hit GPUAcquisitionTimeout — never ran):
// pure-bf16 MFMA (validated R6: absmax 0.125 passes). Repacked dispatches:
// head LSE fused WITH tails (1584 blocks, fills GPU) instead of with the tiny
// projections; proj alone (24 blocks, short). Epilogue reworked to
// max-then-sum (128 exps/thread vs 384). compact fused into split_all.
// Counted vmcnt(4) pipeline, pre-swizzled conflict-free staging, panel-pinned
// swizzle, row compaction.

#define N_ROWS 2048
#define K_IN   1024
#define HEAD_O 4002
#define CUT0   4000
#define CUT1   20000
#define T0_O   16000
#define T1_O   30257
#define H0     512
#define H1     256

// 256-col tiles:
#define HT   16    // ceil(4002/256)
#define T0T  63    // ceil(16000/256)
#define T1T  119   // ceil(30257/256)

typedef __attribute__((ext_vector_type(8))) __bf16 bf16x8;
typedef __attribute__((ext_vector_type(4))) float f32x4;
typedef unsigned short u16;

// ---------------------------------------------------------------------------
__device__ inline u16 f2bf_rne(float f) {
    unsigned u = __builtin_bit_cast(unsigned, f);
    u += 0x7FFFu + ((u >> 16) & 1u);
    return (u16)(u >> 16);
}
__device__ inline float bf2f(u16 b) {
    return __builtin_bit_cast(float, (unsigned)b << 16);
}

__device__ inline void gload_lds16(const u16* g, u16* l) {
    __builtin_amdgcn_global_load_lds(
        (const __attribute__((address_space(1))) void*)g,
        (__attribute__((address_space(3))) void*)l, 16, 0, 0);
}

// ---------------------------------------------------------------------------
// split_compact: blocks 0..2047 convert all six fp32 operands to bf16;
// blocks 2048..2055 do the row compaction (independent work, fused launch).
// ---------------------------------------------------------------------------
__global__ __launch_bounds__(256)
void split_compact(const float* __restrict__ s0, const float* __restrict__ s1,
                   const float* __restrict__ s2, const float* __restrict__ s3,
                   const float* __restrict__ s4, const float* __restrict__ s5,
                   u16* __restrict__ h0, u16* __restrict__ h1, u16* __restrict__ h2,
                   u16* __restrict__ h3, u16* __restrict__ h4, u16* __restrict__ h5,
                   const int* __restrict__ tgt, int* __restrict__ cnt,
                   int* __restrict__ rowOf0, int* __restrict__ cidx0,
                   int* __restrict__ rowOf1, int* __restrict__ cidx1)
{
    if (blockIdx.x >= 2048) {           // ---- compaction tail blocks
        const int row = (blockIdx.x - 2048) * 256 + threadIdx.x;
        if (row >= N_ROWS) return;
        const int tg = tgt[row];
        if (tg >= CUT0 && tg < CUT1) {
            const int s = atomicAdd(&cnt[0], 1);
            rowOf0[s] = row; cidx0[row] = s;
        } else if (tg >= CUT1) {
            const int s = atomicAdd(&cnt[1], 1);
            rowOf1[s] = row; cidx1[row] = s;
        }
        return;
    }
    constexpr int e0 = (N_ROWS * K_IN) / 4;
    constexpr int e1 = e0 + (HEAD_O * K_IN) / 4;
    constexpr int e2 = e1 + (H0 * K_IN) / 4;
    constexpr int e3 = e2 + (H1 * K_IN) / 4;
    constexpr int e4 = e3 + (T0_O * H0) / 4;
    constexpr int e5 = e4 + (T1_O * H1) / 4;
    for (int i = blockIdx.x * 256 + threadIdx.x; i < e5; i += 2048 * 256) {
        const float* src; u16* h; int off;
        if      (i < e0) { src = s0; h = h0; off = i; }
        else if (i < e1) { src = s1; h = h1; off = i - e0; }
        else if (i < e2) { src = s2; h = h2; off = i - e1; }
        else if (i < e3) { src = s3; h = h3; off = i - e2; }
        else if (i < e4) { src = s4; h = h4; off = i - e3; }
        else             { src = s5; h = h5; off = i - e4; }
        const float4 v = ((const float4*)src)[off];
        ushort4 hv;
        hv.x = f2bf_rne(v.x); hv.y = f2bf_rne(v.y);
        hv.z = f2bf_rne(v.z); hv.w = f2bf_rne(v.w);
        ((ushort4*)h)[off] = hv;
    }
}

// ---------------------------------------------------------------------------
// Panel-pinned swizzle: 64 consecutive bids = 8 panels x 8 rowts (same panel
// => same XCD under round-robin). Tail (T % 8) linear.
// ---------------------------------------------------------------------------
__device__ inline void map8(int bid, int T, int& panel, int& rowt)
{
    const int full = T & ~7;
    const int fb = full << 3;
    if (bid < fb) {
        panel = ((bid >> 6) << 3) + (bid & 7);
        rowt  = (bid >> 3) & 7;
    } else {
        const int l = bid - fb;
        panel = full + (l >> 3);
        rowt  = l & 7;
    }
}

// ---------------------------------------------------------------------------
// gemm256_core: D = A[M,K] @ B[O,K]^T (bf16 in, fp32 acc) on a 256x256 tile,
// 8 waves (2x4), each wave 128x64 output (8x4 fragments of 16x16x32).
// 64KB LDS double-buffer, counted vmcnt(4). 16B k-slots XOR-swizzled
// (slot = kg ^ ((row>>1)&3)) via pre-swizzled GLOBAL sources.
//   LSE=true : per-row online-LSE partials (max,sumexp) -> Pm/Ps (stride T).
//   LSE=false: store bf16 C -> Ch.
// ---------------------------------------------------------------------------
template<bool LSE>
__device__ __forceinline__ void gemm256_core(
    u16* lds,
    const u16* __restrict__ A, const u16* __restrict__ B,
    int K, int O, int T, int bx, int by,
    const int* __restrict__ rowIdx,
    float* __restrict__ Pm, float* __restrict__ Ps,
    u16* __restrict__ Ch)
{
    const int t = threadIdx.x;
    const int lane = t & 63;
    const int w = t >> 6;
    const int row0 = by * 256, col0 = bx * 256;
    const int kg = lane >> 4, li = lane & 15;
    const int wr = w >> 2, wc = w & 3;   // 2 x 4 wave grid

    // staging: 4 gload_lds per thread per K-step (2 planes x 2 row-halves)
    const u16* gsrc[4];
    {
        const int slot = t & 3;
        const int rbase = t >> 2;                 // 0..127
        #pragma unroll
        for (int i = 0; i < 4; ++i) {
            const int p = i >> 1, half = i & 1;
            const int rl = half * 128 + rbase;
            const int kd = (slot ^ ((rl >> 1) & 3)) * 8;   // elems
            const u16* base; int grow;
            if (p == 0) {
                grow = row0 + rl;
                if (rowIdx) grow = rowIdx[grow] & (N_ROWS - 1);
                base = A;
            } else {
                grow = col0 + rl; if (grow > O - 1) grow = O - 1;
                base = B;
            }
            gsrc[i] = base + (size_t)grow * K + kd;
        }
    }
    u16* ldsb = lds + t * 8;   // linear per-thread LDS dest

    // fragment byte-offsets within a 32KB buffer (A @ 0, B @ 16KB)
    int aoff[8], boff[4];
    #pragma unroll
    for (int m = 0; m < 8; ++m) {
        const int ar = wr * 128 + m * 16 + li;
        aoff[m] = ar * 64 + ((kg ^ ((ar >> 1) & 3)) << 4);
    }
    #pragma unroll
    for (int n = 0; n < 4; ++n) {
        const int bc = wc * 64 + n * 16 + li;
        boff[n] = 16384 + bc * 64 + ((kg ^ ((bc >> 1) & 3)) << 4);
    }

    f32x4 acc[8][4];
    #pragma unroll
    for (int m = 0; m < 8; ++m)
        #pragma unroll
        for (int n = 0; n < 4; ++n) acc[m][n] = (f32x4){0.f, 0.f, 0.f, 0.f};

    const char* ldsc = (const char*)lds;
    const int nsteps = K >> 5;   // 32 / 16 / 8

    auto compute_step = [&](const char* bufc) {
        bf16x8 fb[4];
        #pragma unroll
        for (int n = 0; n < 4; ++n) fb[n] = *(const bf16x8*)(bufc + boff[n]);
        __builtin_amdgcn_s_setprio(1);
        #pragma unroll
        for (int m = 0; m < 8; ++m) {
            const bf16x8 fa = *(const bf16x8*)(bufc + aoff[m]);
            #pragma unroll
            for (int n = 0; n < 4; ++n)
                acc[m][n] = __builtin_amdgcn_mfma_f32_16x16x32_bf16(fa, fb[n], acc[m][n], 0, 0, 0);
        }
        __builtin_amdgcn_s_setprio(0);
    };

    // prologue: stage buf0 (4 loads outstanding)
    #pragma unroll
    for (int i = 0; i < 4; ++i)
        gload_lds16(gsrc[i], ldsb + (i >> 1) * 8192 + (i & 1) * 4096);

    for (int ks = 0; ks < nsteps - 1; ++ks) {
        const int cur = ks & 1;
        {   // issue next tile into the other buffer (8 outstanding)
            const int nxt = (cur ^ 1) * 16384;   // shorts
            const int kof = (ks + 1) * 32;
            #pragma unroll
            for (int i = 0; i < 4; ++i)
                gload_lds16(gsrc[i] + kof, ldsb + nxt + (i >> 1) * 8192 + (i & 1) * 4096);
        }
        asm volatile("s_waitcnt vmcnt(4)" ::: "memory");  // cur's 4 landed
        __builtin_amdgcn_s_barrier();                     // ... in every wave
        compute_step(ldsc + cur * 32768);
        asm volatile("" ::: "memory");                    // pin reads above bar
        __builtin_amdgcn_s_barrier();                     // reads done before overwrite
    }
    // peeled last step
    asm volatile("s_waitcnt vmcnt(0)" ::: "memory");
    __builtin_amdgcn_s_barrier();
    compute_step(ldsc + ((nsteps - 1) & 1) * 32768);
    asm volatile("" ::: "memory");
    __builtin_amdgcn_s_barrier();                         // before LDS reuse

    if (LSE) {
        // C/D layout (HW-verified): col = li, row = kg*4 + reg.
        // Max-then-sum: plain max reduce (no exp), 4 exps/lane, plain sum
        // reduce. Invalid cols -> -FLT_MAX (exp underflows to 0; all-invalid
        // wc-groups flush to 0 via exp(-inf) in the combines below).
        float* pmS = (float*)lds;            // [256][4]
        float* psS = (float*)lds + 1024;
        #pragma unroll
        for (int m = 0; m < 8; ++m) {
            #pragma unroll
            for (int r = 0; r < 4; ++r) {
                const int row_l = wr * 128 + m * 16 + kg * 4 + r;
                float vv[4];
                #pragma unroll
                for (int n = 0; n < 4; ++n) {
                    const int c = col0 + wc * 64 + n * 16 + li;
                    vv[n] = (c < O) ? acc[m][n][r] : -FLT_MAX;
                }
                float mx = fmaxf(fmaxf(vv[0], vv[1]), fmaxf(vv[2], vv[3]));
                #pragma unroll
                for (int off = 1; off < 16; off <<= 1)
                    mx = fmaxf(mx, __shfl_xor(mx, off));
                float sm = __expf(vv[0] - mx) + __expf(vv[1] - mx)
                         + __expf(vv[2] - mx) + __expf(vv[3] - mx);
                #pragma unroll
                for (int off = 1; off < 16; off <<= 1)
                    sm += __shfl_xor(sm, off);
                if (li == 0) { pmS[row_l * 4 + wc] = mx; psS[row_l * 4 + wc] = sm; }
            }
        }
        __syncthreads();
        if (t < 256) {
            float M = -FLT_MAX, S = 0.f;
            #pragma unroll
            for (int q = 0; q < 4; ++q) {
                const float mq = pmS[t * 4 + q], sq = psS[t * 4 + q];
                const float M2 = fmaxf(M, mq);
                S = S * __expf(M - M2) + sq * __expf(mq - M2);
                M = M2;
            }
            Pm[(size_t)(row0 + t) * T + bx] = M;
            Ps[(size_t)(row0 + t) * T + bx] = S;
        }
    } else {
        // projection epilogue (O % 256 == 0): bf16 plane
        #pragma unroll
        for (int m = 0; m < 8; ++m)
            #pragma unroll
            for (int n = 0; n < 4; ++n)
                #pragma unroll
                for (int r = 0; r < 4; ++r) {
                    const int row = row0 + wr * 128 + m * 16 + kg * 4 + r;
                    const int col = col0 + wc * 64 + n * 16 + li;
                    Ch[(size_t)row * O + col] = f2bf_rne(acc[m][n][r]);
                }
    }
}

// ---------------------------------------------------------------------------
// Dispatch: both hidden projections (24 blocks; short, K=1024).
// ---------------------------------------------------------------------------
__global__ __launch_bounds__(512)
void proj(const u16* __restrict__ ih,
          const u16* __restrict__ w10h, const u16* __restrict__ w11h,
          const int* __restrict__ cnt,
          const int* __restrict__ rowOf0, const int* __restrict__ rowOf1,
          u16* __restrict__ t0hh, u16* __restrict__ t1hh)
{
    __shared__ u16 lds[32768];   // 64 KB
    const int bid = blockIdx.x;
    if (bid < 16) {                      // t0: O=512 -> 2 col-tiles x 8 rowts
        const int bx = bid >> 3, by = bid & 7;
        if (by * 256 >= cnt[0]) return;
        gemm256_core<false>(lds, ih, w10h, K_IN, H0, 2, bx, by,
                            rowOf0, nullptr, nullptr, t0hh);
    } else {                             // t1: O=256 -> 1 col-tile x 8 rowts
        const int by = (bid - 16) & 7;
        if (by * 256 >= cnt[1]) return;
        gemm256_core<false>(lds, ih, w11h, K_IN, H1, 1, 0, by,
                            rowOf1, nullptr, nullptr, t1hh);
    }
}

// ---------------------------------------------------------------------------
// Dispatch: ALL LSE GEMMs — head (128 blocks, K=1024, longest: issued first)
// + tail0 (504, K=512) + tail1 (952, K=256). 1584 blocks fills the GPU.
// ---------------------------------------------------------------------------
__global__ __launch_bounds__(512)
void lse_all(const u16* __restrict__ ih,   const u16* __restrict__ hwh,
             const u16* __restrict__ t0hh, const u16* __restrict__ w20h,
             const u16* __restrict__ t1hh, const u16* __restrict__ w21h,
             const int* __restrict__ cnt,
             float* __restrict__ hPm, float* __restrict__ hPs,
             float* __restrict__ p0m, float* __restrict__ p0s,
             float* __restrict__ p1m, float* __restrict__ p1s)
{
    __shared__ u16 lds[32768];
    const int bid = blockIdx.x;
    int bx, by;
    if (bid < HT * 8) {                                     // head
        map8(bid, HT, bx, by);
        gemm256_core<true>(lds, ih, hwh, K_IN, HEAD_O, HT, bx, by,
                           nullptr, hPm, hPs, nullptr);
    } else if (bid < HT * 8 + T0T * 8) {                    // tail0
        map8(bid - HT * 8, T0T, bx, by);
        if (by * 256 >= cnt[0]) return;
        gemm256_core<true>(lds, t0hh, w20h, H0, T0_O, T0T, bx, by,
                           nullptr, p0m, p0s, nullptr);
    } else {                                                // tail1
        map8(bid - HT * 8 - T0T * 8, T1T, bx, by);
        if (by * 256 >= cnt[1]) return;
        gemm256_core<true>(lds, t1hh, w21h, H1, T1_O, T1T, bx, by,
                           nullptr, p1m, p1s, nullptr);
    }
}

// ---------------------------------------------------------------------------
// finalize (R6-verified): combine LSE partials + recompute target logits.
// ---------------------------------------------------------------------------
__device__ inline float block_sum(float v, float* sm)
{
#pragma unroll
    for (int off = 32; off > 0; off >>= 1) v += __shfl_xor(v, off);
    __syncthreads();
    if ((threadIdx.x & 63) == 0) sm[threadIdx.x >> 6] = v;
    __syncthreads();
    return sm[0] + sm[1] + sm[2] + sm[3];
}

__device__ inline void block_lse(float& m, float& s, float* smm, float* sms)
{
#pragma unroll
    for (int off = 32; off > 0; off >>= 1) {
        const float mo = __shfl_xor(m, off);
        const float so = __shfl_xor(s, off);
        const float M2 = fmaxf(m, mo);
        s = s * __expf(m - M2) + so * __expf(mo - M2);
        m = M2;
    }
    __syncthreads();
    if ((threadIdx.x & 63) == 0) { smm[threadIdx.x >> 6] = m; sms[threadIdx.x >> 6] = s; }
    __syncthreads();
    const float M2 = fmaxf(fmaxf(smm[0], smm[1]), fmaxf(smm[2], smm[3]));
    const float S  = sms[0] * __expf(smm[0] - M2) + sms[1] * __expf(smm[1] - M2)
                   + sms[2] * __expf(smm[2] - M2) + sms[3] * __expf(smm[3] - M2);
    m = M2; s = S;
}

__device__ inline void local_lse(const float* __restrict__ Pm,
                                 const float* __restrict__ Ps,
                                 int T, float& m, float& s)
{
    m = -FLT_MAX; s = 0.f;
    for (int i = threadIdx.x; i < T; i += 256) {
        const float mi = Pm[i], si = Ps[i];
        const float M2 = fmaxf(m, mi);
        s = s * __expf(m - M2) + si * __expf(mi - M2);
        m = M2;
    }
}

__global__ __launch_bounds__(256)
void finalize(const float* __restrict__ inp, const int* __restrict__ tgt,
              const float* __restrict__ head_w,
              const int* __restrict__ cidx0, const int* __restrict__ cidx1,
              const u16* __restrict__ t0hh, const u16* __restrict__ t1hh,
              const float* __restrict__ hPm, const float* __restrict__ hPs, int hT,
              const float* __restrict__ p0m, const float* __restrict__ p0s, int T0,
              const float* __restrict__ p1m, const float* __restrict__ p1s, int T1,
              const float* __restrict__ t0_w2, const float* __restrict__ t1_w2,
              float* __restrict__ out)
{
    __shared__ float sm[4], ss[4];
    const int row = blockIdx.x, t = threadIdx.x;
    const int tg = tgt[row];
    const bool in1 = (tg >= CUT0) && (tg < CUT1);
    const bool in2 = (tg >= CUT1);
    const int g = (tg < CUT0) ? tg : (in1 ? CUT0 : CUT0 + 1);
    const int c0 = in1 ? cidx0[row] : 0;
    const int c1 = in2 ? cidx1[row] : 0;

    float d;
    {
        const float4 a = *(const float4*)(inp + (size_t)row * K_IN + t * 4);
        const float4 b = *(const float4*)(head_w + (size_t)g * K_IN + t * 4);
        d = a.x * b.x + a.y * b.y + a.z * b.z + a.w * b.w;
    }
    const float dot_h = block_sum(d, sm);

    int r0 = tg - CUT0; r0 = r0 < 0 ? 0 : (r0 > T0_O - 1 ? T0_O - 1 : r0);
    d = 0.f;
    if (t < 128) {
        const ushort4 a = *(const ushort4*)(t0hh + (size_t)c0 * H0 + t * 4);
        const float4  b = *(const float4*)(t0_w2 + (size_t)r0 * H0 + t * 4);
        d = bf2f(a.x) * b.x + bf2f(a.y) * b.y + bf2f(a.z) * b.z + bf2f(a.w) * b.w;
    }
    const float dot0 = block_sum(d, sm);

    int r1 = tg - CUT1; r1 = r1 < 0 ? 0 : (r1 > T1_O - 1 ? T1_O - 1 : r1);
    d = 0.f;
    if (t < 64) {
        const ushort4 a = *(const ushort4*)(t1hh + (size_t)c1 * H1 + t * 4);
        const float4  b = *(const float4*)(t1_w2 + (size_t)r1 * H1 + t * 4);
        d = bf2f(a.x) * b.x + bf2f(a.y) * b.y + bf2f(a.z) * b.z + bf2f(a.w) * b.w;
    }
    const float dot1 = block_sum(d, sm);

    float m, s;
    local_lse(hPm + (size_t)row * hT, hPs + (size_t)row * hT, hT, m, s);
    block_lse(m, s, sm, ss);
    const float lse_h = m + logf(s);

    local_lse(p0m + (size_t)c0 * T0, p0s + (size_t)c0 * T0, T0, m, s);
    block_lse(m, s, sm, ss);
    const float lse_0 = m + logf(s);

    local_lse(p1m + (size_t)c1 * T1, p1s + (size_t)c1 * T1, T1, m, s);
    block_lse(m, s, sm, ss);
    const float lse_1 = m + logf(s);

    if (t == 0) {
        float res = dot_h - lse_h;
        if (in1) res += dot0 - lse_0;
        if (in2) res += dot1 - lse_1;
        out[row] = -res;
    }
}

// ---------------------------------------------------------------------------
extern "C" void kernel_launch(void* const* d_in, const int* in_sizes, int n_in,
                              void* d_out, int out_size, void* d_ws, size_t ws_size,
                              hipStream_t stream)
{
    const float* inp    = (const float*)d_in[0];
    const int*   tgt    = (const int*)  d_in[1];
    const float* head_w = (const float*)d_in[2];
    const float* t0_w1  = (const float*)d_in[3];
    const float* t0_w2  = (const float*)d_in[4];
    const float* t1_w1  = (const float*)d_in[5];
    const float* t1_w2  = (const float*)d_in[6];
    float* out = (float*)d_out;

    char* p = (char*)d_ws;
    #define ALLOC(name, type, count) \
        type* name = (type*)p; p += (((size_t)(count) * sizeof(type)) + 255) & ~(size_t)255;
    ALLOC(hPm,  float, (size_t)N_ROWS * HT)
    ALLOC(hPs,  float, (size_t)N_ROWS * HT)
    ALLOC(p0m,  float, (size_t)N_ROWS * T0T)
    ALLOC(p0s,  float, (size_t)N_ROWS * T0T)
    ALLOC(p1m,  float, (size_t)N_ROWS * T1T)
    ALLOC(p1s,  float, (size_t)N_ROWS * T1T)
    ALLOC(ih,   u16, (size_t)N_ROWS * K_IN)
    ALLOC(hwh,  u16, (size_t)HEAD_O * K_IN)
    ALLOC(w10h, u16, (size_t)H0 * K_IN)
    ALLOC(w11h, u16, (size_t)H1 * K_IN)
    ALLOC(w20h, u16, (size_t)T0_O * H0)
    ALLOC(w21h, u16, (size_t)T1_O * H1)
    ALLOC(t0hh, u16, (size_t)N_ROWS * H0)
    ALLOC(t1hh, u16, (size_t)N_ROWS * H1)
    ALLOC(cnt,    int, 2)
    ALLOC(rowOf0, int, N_ROWS)
    ALLOC(cidx0,  int, N_ROWS)
    ALLOC(rowOf1, int, N_ROWS)
    ALLOC(cidx1,  int, N_ROWS)
    #undef ALLOC

    hipMemsetAsync(cnt, 0, 2 * sizeof(int), stream);

    // bf16 conversion of all operands + row compaction (fused launch)
    split_compact<<<dim3(2048 + 8), dim3(256), 0, stream>>>(
        inp, head_w, t0_w1, t1_w1, t0_w2, t1_w2,
        ih, hwh, w10h, w11h, w20h, w21h,
        tgt, cnt, rowOf0, cidx0, rowOf1, cidx1);

    // hidden projections (small; 24 blocks)
    proj<<<dim3(24), dim3(512), 0, stream>>>(
        ih, w10h, w11h, cnt, rowOf0, rowOf1, t0hh, t1hh);

    // all LSE GEMMs fused: head + tail0 + tail1 (1584 blocks)
    lse_all<<<dim3(HT * 8 + T0T * 8 + T1T * 8), dim3(512), 0, stream>>>(
        ih, hwh, t0hh, w20h, t1hh, w21h, cnt,
        hPm, hPs, p0m, p0s, p1m, p1s);

    // per-row assembly
    finalize<<<dim3(N_ROWS), dim3(256), 0, stream>>>(
        inp, tgt, head_w, cidx0, cidx1, t0hh, t1hh,
        hPm, hPs, HT, p0m, p0s, T0T, p1m, p1s, T1T, t0_w2, t1_w2, out);
}